// Round 8
// baseline (243.943 us; speedup 1.0000x reference)
//
#include <hip/hip_runtime.h>
#include <cstdint>
#include <cstddef>

#define TOKENS 8192
#define DIN    4096
#define DOUT   4096

typedef int int4v  __attribute__((ext_vector_type(4)));
typedef int int16v __attribute__((ext_vector_type(16)));

// ---------------------------------------------------------------------------
// Kernel 1: per-token dynamic quantization (unchanged, near HBM-bound).
// ---------------------------------------------------------------------------
__global__ __launch_bounds__(256) void quant_rows(const float* __restrict__ x,
                                                  int* __restrict__ xq,
                                                  float* __restrict__ ascale,
                                                  int* __restrict__ rsum) {
  const int row = blockIdx.x;
  const int t = threadIdx.x;
  const float4* xr = (const float4*)(x + (size_t)row * DIN);
  float4 v[4];
#pragma unroll
  for (int i = 0; i < 4; ++i) v[i] = xr[i * 256 + t];

  float m = 0.f;
#pragma unroll
  for (int i = 0; i < 4; ++i) {
    m = fmaxf(m, fabsf(v[i].x)); m = fmaxf(m, fabsf(v[i].y));
    m = fmaxf(m, fabsf(v[i].z)); m = fmaxf(m, fabsf(v[i].w));
  }
#pragma unroll
  for (int off = 32; off; off >>= 1) m = fmaxf(m, __shfl_xor(m, off));

  __shared__ float wmax[4];
  __shared__ int   wsum[4];
  const int lane = t & 63, wid = t >> 6;
  if (lane == 0) wmax[wid] = m;
  __syncthreads();
  m = fmaxf(fmaxf(wmax[0], wmax[1]), fmaxf(wmax[2], wmax[3]));

  const float s = m * (1.0f / 127.0f);
  const float sdiv = (m > 0.f) ? s : 1.0f;

  int ssum = 0;
#pragma unroll
  for (int i = 0; i < 4; ++i) {
    float q;
    q = fminf(fmaxf(rintf(v[i].x / sdiv), -127.f), 127.f); const int b0 = (int)q;
    q = fminf(fmaxf(rintf(v[i].y / sdiv), -127.f), 127.f); const int b1 = (int)q;
    q = fminf(fmaxf(rintf(v[i].z / sdiv), -127.f), 127.f); const int b2 = (int)q;
    q = fminf(fmaxf(rintf(v[i].w / sdiv), -127.f), 127.f); const int b3 = (int)q;
    ssum += b0 + b1 + b2 + b3;
    xq[(size_t)row * 1024 + i * 256 + t] =
        (b0 & 255) | ((b1 & 255) << 8) | ((b2 & 255) << 16) | ((b3 & 255) << 24);
  }
#pragma unroll
  for (int off = 32; off; off >>= 1) ssum += __shfl_xor(ssum, off);
  if (lane == 0) wsum[wid] = ssum;
  __syncthreads();
  if (t == 0) {
    rsum[row]   = wsum[0] + wsum[1] + wsum[2] + wsum[3];
    ascale[row] = s;
  }
}

// ---------------------------------------------------------------------------
// Kernel 2: weight int32 -> packed int8 (unchanged).
// ---------------------------------------------------------------------------
__global__ __launch_bounds__(256) void wconv(const int* __restrict__ w,
                                             int* __restrict__ w8) {
  const int idx = blockIdx.x * 256 + threadIdx.x;
  const int4 v = ((const int4*)w)[idx];
  w8[idx] = (v.x & 255) | ((v.y & 255) << 8) | ((v.z & 255) << 16) | ((v.w & 255) << 24);
}

// ---------------------------------------------------------------------------
// Kernel 3: i8 GEMM, 256x256 tile. A staged via LDS ring; B loaded DIRECT
// global->register in MFMA fragment layout (L2-resident, VMEM pipe idle).
//  - 512 thr = 8 waves (2M x 4N), per-wave 128x64 C, mfma_i32_32x32x32_i8
//  - LDS 64 KiB: 4-buffer ring of A-tiles (2 units x 8 KiB each); depth-3
//    staging (tile T stages A(T+3)); end-of-tile vmcnt(6)+barrier forces
//    A(T+2) complete exactly when tile T+1 pre-reads it. Never drains to 0.
//  - B: 4x global_load_dwordx4 per wave per tile (ni x khalf), register
//    double-buffered bC/bN with name swap (2-tile unrolled loop, static idx).
//    Compiler's own reg-dep vmcnt covers B; in-order vmcnt retirement means
//    a forced B also forces all older A-stages (m135 semantics).
//  - fragment swizzle + pre-permuted staging source: verified-passing R7 pair.
// ---------------------------------------------------------------------------
#define GLOAD(G_, L_) __builtin_amdgcn_global_load_lds(                       \
      (const __attribute__((address_space(1))) void*)(G_),                    \
      (__attribute__((address_space(3))) void*)(L_), 16, 0, 0)

// Tile body: stage A(T+3) | load B(T+1)->BN | ds_read aB=k1(T) |
//            MFMA k0 (aA x BC[0..1]) | ds_read aA=k0(T+1) |
//            MFMA k1 (aB x BC[2..3]) | vmcnt(N) barrier
#define TILE_BODY(T_, BC_, BN_, STG_, LDB_, LDA_, VMN_)                       \
  do {                                                                        \
    const int rbO = ((T_) & 3) * 16384;                                       \
    if (STG_) {                                                               \
      char* Wb = lds + (((T_) + 3) & 3) * 16384;                              \
      const size_t ko = (size_t)((T_) + 3) * 64;                              \
      GLOAD(gA0 + ko, Wb + ldst);                                             \
      GLOAD(gA1 + ko, Wb + 8192 + ldst);                                      \
    }                                                                         \
    if (LDB_) {                                                               \
      const size_t kb = (size_t)((T_) + 1) * 64;                              \
      BN_[0] = *(const int4v*)(gB00 + kb);                                    \
      BN_[1] = *(const int4v*)(gB10 + kb);                                    \
      BN_[2] = *(const int4v*)(gB01 + kb);                                    \
      BN_[3] = *(const int4v*)(gB11 + kb);                                    \
    }                                                                         \
    _Pragma("unroll")                                                         \
    for (int mi = 0; mi < 4; ++mi)                                            \
      aB[mi] = *(const int4v*)(lds + rbO + aoff1 + mi * 2048);                \
    __builtin_amdgcn_s_setprio(1);                                            \
    _Pragma("unroll")                                                         \
    for (int mi = 0; mi < 4; ++mi) {                                          \
      acc[mi][0] = __builtin_amdgcn_mfma_i32_32x32x32_i8(aA[mi], BC_[0], acc[mi][0], 0, 0, 0); \
      acc[mi][1] = __builtin_amdgcn_mfma_i32_32x32x32_i8(aA[mi], BC_[1], acc[mi][1], 0, 0, 0); \
    }                                                                         \
    __builtin_amdgcn_s_setprio(0);                                            \
    if (LDA_) {                                                               \
      const int rnO = (((T_) + 1) & 3) * 16384;                               \
      _Pragma("unroll")                                                       \
      for (int mi = 0; mi < 4; ++mi)                                          \
        aA[mi] = *(const int4v*)(lds + rnO + aoff0 + mi * 2048);              \
    }                                                                         \
    __builtin_amdgcn_s_setprio(1);                                            \
    _Pragma("unroll")                                                         \
    for (int mi = 0; mi < 4; ++mi) {                                          \
      acc[mi][0] = __builtin_amdgcn_mfma_i32_32x32x32_i8(aB[mi], BC_[2], acc[mi][0], 0, 0, 0); \
      acc[mi][1] = __builtin_amdgcn_mfma_i32_32x32x32_i8(aB[mi], BC_[3], acc[mi][1], 0, 0, 0); \
    }                                                                         \
    __builtin_amdgcn_s_setprio(0);                                            \
    if ((VMN_) == 6)      asm volatile("s_waitcnt vmcnt(6)" ::: "memory");    \
    else if ((VMN_) == 4) asm volatile("s_waitcnt vmcnt(4)" ::: "memory");    \
    if ((VMN_) >= 0) __builtin_amdgcn_s_barrier();                            \
  } while (0)

__global__ __launch_bounds__(512, 2) void gemm_i8(
    const char* __restrict__ xq, const char* __restrict__ w8,
    const float* __restrict__ ascale, const int* __restrict__ rsum,
    const float* __restrict__ wscale, const float* __restrict__ woff,
    const float* __restrict__ bias, float* __restrict__ y) {

  // 4 ring buffers x [Aunit0|Aunit1] x 8 KiB = 64 KiB (A only)
  __shared__ __align__(16) char lds[65536];

  const int bid = blockIdx.x;
  const int tm = bid >> 4;            // 32 M-tiles
  const int tn = bid & 15;            // 16 N-tiles
  const int t = threadIdx.x;          // 0..511
  const int lane = t & 63, wid = t >> 6;
  const int wmI = wid >> 2;           // 0..1 (M)
  const int wnI = wid & 3;            // 0..3 (N)

  // ---- A staging source: involution (R7, verified passing) ----
  const int S = (t * 16) ^ (((t >> 3) & 3) << 4) ^ (((t >> 6) & 1) << 6);
  const int srow = S >> 6;                              // 0..127 within unit
  const int scol = S & 63;

  const char* gA0 = xq + (size_t)(tm * 256 + srow) * DIN + scol;
  const char* gA1 = gA0 + (size_t)128 * DIN;
  const int ldst = t * 16;                              // LINEAR LDS dest

  // ---- A fragment read offsets (R7 involution, verified passing) ----
  const int mask  = (((lane >> 1) & 3) << 4) ^ (((lane >> 4) & 1) << 6);
  const int arow  = (lane & 31) * 64 + (lane >> 5) * 16;
  const int aoff0 = wmI * 8192 + ((arow +  0) ^ mask);
  const int aoff1 = wmI * 8192 + ((arow + 32) ^ mask);

  // ---- B direct-load lane pointers (fragment layout: row=lane&31,
  //      16B chunk (lane>>5)*16, khalf +32; ni stride 32 cols) ----
  const char* gBL = w8 + (size_t)(tn * 256 + wnI * 64 + (lane & 31)) * DIN
                       + (lane >> 5) * 16;
  const char* gB00 = gBL;                 // ni=0, k-half 0
  const char* gB10 = gBL + 32 * DIN;      // ni=1, k-half 0
  const char* gB01 = gBL + 32;            // ni=0, k-half 1
  const char* gB11 = gBL + 32 * DIN + 32; // ni=1, k-half 1

  int16v acc[4][2];
#pragma unroll
  for (int mi = 0; mi < 4; ++mi)
#pragma unroll
    for (int ni = 0; ni < 2; ++ni)
#pragma unroll
      for (int rg = 0; rg < 16; ++rg) acc[mi][ni][rg] = 0;

  int4v aA[4], aB[4], bC[4], bN[4];

  // ---- prologue: B(0) -> bC; stage A(0),A(1),A(2); wait B(0),A(0),A(1) ----
  bC[0] = *(const int4v*)gB00;
  bC[1] = *(const int4v*)gB10;
  bC[2] = *(const int4v*)gB01;
  bC[3] = *(const int4v*)gB11;
#pragma unroll
  for (int p = 0; p < 3; ++p) {
    char* Wb = lds + p * 16384;
    GLOAD(gA0 + p * 64, Wb + ldst);
    GLOAD(gA1 + p * 64, Wb + 8192 + ldst);
  }
  asm volatile("s_waitcnt vmcnt(2)" ::: "memory");   // allow A(2) in flight
  __builtin_amdgcn_s_barrier();
#pragma unroll
  for (int mi = 0; mi < 4; ++mi)
    aA[mi] = *(const int4v*)(lds + aoff0 + mi * 2048);

  // ---- main loop: 64 K-tiles ----
  for (int T = 0; T < 60; T += 2) {
    TILE_BODY(T,     bC, bN, 1, 1, 1, 6);
    TILE_BODY(T + 1, bN, bC, 1, 1, 1, 6);
  }
  TILE_BODY(60, bC, bN, 1, 1, 1, 6);   // stages A(63), loads B(61)
  TILE_BODY(61, bN, bC, 0, 1, 1, 4);   // loads B(62); forces A(63),B(61)
  TILE_BODY(62, bC, bN, 0, 1, 1, -1);  // loads B(63); no barrier needed
  TILE_BODY(63, bN, bC, 0, 0, 0, -1);

  // ---- epilogue: zp-correction + dequant + bias ----
  // C/D 32x32: col = lane&31, row = (rg&3) + 8*(rg>>2) + 4*(lane>>5)
  const int rb0 = tm * 256 + wmI * 128 + 4 * (lane >> 5);
  const int cb0 = tn * 256 + wnI * 64 + (lane & 31);
  const float ws0 = wscale[cb0],      ws1 = wscale[cb0 + 32];
  const float wo0 = woff[cb0],        wo1 = woff[cb0 + 32];
  const float bi0 = bias[cb0],        bi1 = bias[cb0 + 32];
#pragma unroll
  for (int mi = 0; mi < 4; ++mi) {
#pragma unroll
    for (int rg = 0; rg < 16; ++rg) {
      const int r = rb0 + mi * 32 + (rg & 3) + 8 * (rg >> 2);
      const float as_ = ascale[r];
      const float rs_ = (float)rsum[r];
      y[(size_t)r * DOUT + cb0]      = ((float)acc[mi][0][rg] + rs_ * wo0) * (as_ * ws0) + bi0;
      y[(size_t)r * DOUT + cb0 + 32] = ((float)acc[mi][1][rg] + rs_ * wo1) * (as_ * ws1) + bi1;
    }
  }
}

// ---------------------------------------------------------------------------
extern "C" void kernel_launch(void* const* d_in, const int* in_sizes, int n_in,
                              void* d_out, int out_size, void* d_ws, size_t ws_size,
                              hipStream_t stream) {
  const float* x      = (const float*)d_in[0];
  const int*   w      = (const int*)  d_in[1];
  const float* wscale = (const float*)d_in[2];
  const float* woff   = (const float*)d_in[3];
  const float* bias   = (const float*)d_in[4];
  float* y = (float*)d_out;

  char* ws = (char*)d_ws;
  char*  xq     = ws;                                 // 33,554,432 B
  char*  w8     = ws + (size_t)TOKENS * DIN;          // 16,777,216 B
  float* ascale = (float*)(w8 + (size_t)DOUT * DIN);  // 32,768 B
  int*   rsum   = (int*)(ascale + TOKENS);            // 32,768 B

  hipLaunchKernelGGL(quant_rows, dim3(TOKENS), dim3(256), 0, stream,
                     x, (int*)xq, ascale, rsum);
  hipLaunchKernelGGL(wconv, dim3((DOUT * DIN / 4) / 256), dim3(256), 0, stream,
                     w, (int*)w8);
  hipLaunchKernelGGL(gemm_i8, dim3((TOKENS / 256) * (DOUT / 256)), dim3(512), 0, stream,
                     xq, w8, ascale, rsum, wscale, woff, bias, y);
}

// Round 10
// 202.980 us; speedup vs baseline: 1.2018x; 1.2018x over previous
//
#include <hip/hip_runtime.h>
#include <cstdint>
#include <cstddef>

#define TOKENS 8192
#define DIN    4096
#define DOUT   4096

typedef int int4v  __attribute__((ext_vector_type(4)));
typedef int int16v __attribute__((ext_vector_type(16)));

// ---------------------------------------------------------------------------
// Kernel 1: per-token dynamic quantization (unchanged, near HBM-bound).
// ---------------------------------------------------------------------------
__global__ __launch_bounds__(256) void quant_rows(const float* __restrict__ x,
                                                  int* __restrict__ xq,
                                                  float* __restrict__ ascale,
                                                  int* __restrict__ rsum) {
  const int row = blockIdx.x;
  const int t = threadIdx.x;
  const float4* xr = (const float4*)(x + (size_t)row * DIN);
  float4 v[4];
#pragma unroll
  for (int i = 0; i < 4; ++i) v[i] = xr[i * 256 + t];

  float m = 0.f;
#pragma unroll
  for (int i = 0; i < 4; ++i) {
    m = fmaxf(m, fabsf(v[i].x)); m = fmaxf(m, fabsf(v[i].y));
    m = fmaxf(m, fabsf(v[i].z)); m = fmaxf(m, fabsf(v[i].w));
  }
#pragma unroll
  for (int off = 32; off; off >>= 1) m = fmaxf(m, __shfl_xor(m, off));

  __shared__ float wmax[4];
  __shared__ int   wsum[4];
  const int lane = t & 63, wid = t >> 6;
  if (lane == 0) wmax[wid] = m;
  __syncthreads();
  m = fmaxf(fmaxf(wmax[0], wmax[1]), fmaxf(wmax[2], wmax[3]));

  const float s = m * (1.0f / 127.0f);
  const float sdiv = (m > 0.f) ? s : 1.0f;

  int ssum = 0;
#pragma unroll
  for (int i = 0; i < 4; ++i) {
    float q;
    q = fminf(fmaxf(rintf(v[i].x / sdiv), -127.f), 127.f); const int b0 = (int)q;
    q = fminf(fmaxf(rintf(v[i].y / sdiv), -127.f), 127.f); const int b1 = (int)q;
    q = fminf(fmaxf(rintf(v[i].z / sdiv), -127.f), 127.f); const int b2 = (int)q;
    q = fminf(fmaxf(rintf(v[i].w / sdiv), -127.f), 127.f); const int b3 = (int)q;
    ssum += b0 + b1 + b2 + b3;
    xq[(size_t)row * 1024 + i * 256 + t] =
        (b0 & 255) | ((b1 & 255) << 8) | ((b2 & 255) << 16) | ((b3 & 255) << 24);
  }
#pragma unroll
  for (int off = 32; off; off >>= 1) ssum += __shfl_xor(ssum, off);
  if (lane == 0) wsum[wid] = ssum;
  __syncthreads();
  if (t == 0) {
    rsum[row]   = wsum[0] + wsum[1] + wsum[2] + wsum[3];
    ascale[row] = s;
  }
}

// ---------------------------------------------------------------------------
// Kernel 2: weight int32 -> packed int8 (unchanged).
// ---------------------------------------------------------------------------
__global__ __launch_bounds__(256) void wconv(const int* __restrict__ w,
                                             int* __restrict__ w8) {
  const int idx = blockIdx.x * 256 + threadIdx.x;
  const int4 v = ((const int4*)w)[idx];
  w8[idx] = (v.x & 255) | ((v.y & 255) << 8) | ((v.z & 255) << 16) | ((v.w & 255) << 24);
}

// ---------------------------------------------------------------------------
// Kernel 3: i8 GEMM, 256x256 tile, SUPER-STEP schedule (barrier per 2 tiles).
//  - 512 thr = 8 waves (2M x 4N), per-wave 128x64 C, mfma_i32_32x32x32_i8
//  - LDS 128 KiB: ring of 4 tile-buffers [Aunit0|Aunit1|Bunit0|Bunit1]x8KiB
//  - Super-step S (S even): stage tiles {S+2,S+3} up-front (8 gloads);
//    compute tiles S, S+1 with NO intervening barrier (waves drift +-1 tile
//    -> one wave's ds_reads overlap another's MFMAs on the same SIMD);
//    then vmcnt(0)+s_barrier once. Drained loads were issued ~2700 cyc
//    earlier -> drain is ~free. Safety: stage targets (S+2)&3,(S+3)&3 are
//    read only in SS(S-2)/SS(S+2), separated by the barrier -> no WAR for
//    any intra-SS skew; vmcnt(0)+barrier makes ALL waves' stages visible.
//  - sched_barrier(0) after s_barrier pins the post-barrier k0(S+2) read.
//  - R10 FIX: each super-step executes EXACTLY ONCE (R9 ran SUPER(60) twice
//    -> tiles 60,61 double-accumulated -> absmax 74).
// ---------------------------------------------------------------------------
#define GLOAD(G_, L_) __builtin_amdgcn_global_load_lds(                       \
      (const __attribute__((address_space(1))) void*)(G_),                    \
      (__attribute__((address_space(3))) void*)(L_), 16, 0, 0)

#define RD(AV_, BV_, L_, AO_, BO_)                                            \
    _Pragma("unroll")                                                         \
    for (int mi = 0; mi < 4; ++mi)                                            \
      AV_[mi] = *(const int4v*)((L_) + (AO_) + mi * 2048);                    \
    _Pragma("unroll")                                                         \
    for (int ni = 0; ni < 2; ++ni)                                            \
      BV_[ni] = *(const int4v*)((L_) + (BO_) + ni * 2048);

#define MFMA8(AV_, BV_)                                                       \
  __builtin_amdgcn_s_setprio(1);                                              \
  _Pragma("unroll")                                                           \
  for (int mi = 0; mi < 4; ++mi) {                                            \
    acc[mi][0] = __builtin_amdgcn_mfma_i32_32x32x32_i8(AV_[mi], BV_[0], acc[mi][0], 0, 0, 0); \
    acc[mi][1] = __builtin_amdgcn_mfma_i32_32x32x32_i8(AV_[mi], BV_[1], acc[mi][1], 0, 0, 0); \
  }                                                                           \
  __builtin_amdgcn_s_setprio(0);

// Super-step: [stage S+2,S+3] | k1(S)->aB,bB | MFMA k0(S) | k0(S+1)->aA,bA |
//             MFMA k1(S) | k1(S+1)->aB,bB | MFMA k0(S+1) | MFMA k1(S+1) |
//             [vmcnt(0) barrier sched_barrier; k0(S+2)->aA,bA]
#define SUPER(S_, STG_, BAR_)                                                 \
  do {                                                                        \
    if (STG_) {                                                               \
      char* W2 = lds + (((S_) + 2) & 3) * 32768;                              \
      char* W3 = lds + (((S_) + 3) & 3) * 32768;                              \
      const size_t k2 = (size_t)((S_) + 2) * 64;                              \
      const size_t k3 = (size_t)((S_) + 3) * 64;                              \
      GLOAD(gA0 + k2, W2 + ldst);                                             \
      GLOAD(gA1 + k2, W2 + 8192 + ldst);                                      \
      GLOAD(gB0 + k2, W2 + 16384 + ldst);                                     \
      GLOAD(gB1 + k2, W2 + 24576 + ldst);                                     \
      GLOAD(gA0 + k3, W3 + ldst);                                             \
      GLOAD(gA1 + k3, W3 + 8192 + ldst);                                      \
      GLOAD(gB0 + k3, W3 + 16384 + ldst);                                     \
      GLOAD(gB1 + k3, W3 + 24576 + ldst);                                     \
    }                                                                         \
    {                                                                         \
      const char* L0 = lds + ((S_) & 3) * 32768;                              \
      const char* L1 = lds + (((S_) + 1) & 3) * 32768;                        \
      RD(aB, bB, L0, aoff1, boff1)       /* k1(S)   */                        \
      MFMA8(aA, bA)                      /* k0(S)   */                        \
      RD(aA, bA, L1, aoff0, boff0)       /* k0(S+1) */                        \
      MFMA8(aB, bB)                      /* k1(S)   */                        \
      RD(aB, bB, L1, aoff1, boff1)       /* k1(S+1) */                        \
      MFMA8(aA, bA)                      /* k0(S+1) */                        \
      MFMA8(aB, bB)                      /* k1(S+1) */                        \
    }                                                                         \
    if (BAR_) {                                                               \
      asm volatile("s_waitcnt vmcnt(0)" ::: "memory");                        \
      __builtin_amdgcn_s_barrier();                                           \
      __builtin_amdgcn_sched_barrier(0);                                      \
      const char* L2 = lds + (((S_) + 2) & 3) * 32768;                        \
      RD(aA, bA, L2, aoff0, boff0)       /* k0(S+2) */                        \
    }                                                                         \
  } while (0)

__global__ __launch_bounds__(512, 2) void gemm_i8(
    const char* __restrict__ xq, const char* __restrict__ w8,
    const float* __restrict__ ascale, const int* __restrict__ rsum,
    const float* __restrict__ wscale, const float* __restrict__ woff,
    const float* __restrict__ bias, float* __restrict__ y) {

  // 4 ring buffers x [Aunit0|Aunit1|Bunit0|Bunit1] x 8 KiB = 128 KiB
  __shared__ __align__(16) char lds[131072];

  const int bid = blockIdx.x;
  const int tm = bid >> 4;            // 32 M-tiles
  const int tn = bid & 15;            // 16 N-tiles
  const int t = threadIdx.x;          // 0..511
  const int lane = t & 63, wid = t >> 6;
  const int wmI = wid >> 2;           // 0..1 (M)
  const int wnI = wid & 3;            // 0..3 (N)

  // ---- staging source: involution (R7, verified passing) ----
  const int S_ = (t * 16) ^ (((t >> 3) & 3) << 4) ^ (((t >> 6) & 1) << 6);
  const int srow = S_ >> 6;                             // 0..127 within unit
  const int scol = S_ & 63;

  const char* gA0 = xq + (size_t)(tm * 256 + srow) * DIN + scol;
  const char* gA1 = gA0 + (size_t)128 * DIN;
  const char* gB0 = w8 + (size_t)(tn * 256 + srow) * DIN + scol;
  const char* gB1 = gB0 + (size_t)128 * DIN;
  const int ldst = t * 16;                              // LINEAR LDS dest

  // ---- fragment read offsets (R7 involution, verified passing) ----
  const int mask  = (((lane >> 1) & 3) << 4) ^ (((lane >> 4) & 1) << 6);
  const int arow  = (lane & 31) * 64 + (lane >> 5) * 16;
  const int aoff0 = wmI * 8192 + ((arow +  0) ^ mask);
  const int aoff1 = wmI * 8192 + ((arow + 32) ^ mask);
  const int brow  = (wnI & 1) * 4096 + arow;
  const int boff0 = (2 + (wnI >> 1)) * 8192 + ((brow +  0) ^ mask);
  const int boff1 = (2 + (wnI >> 1)) * 8192 + ((brow + 32) ^ mask);

  int16v acc[4][2];
#pragma unroll
  for (int mi = 0; mi < 4; ++mi)
#pragma unroll
    for (int ni = 0; ni < 2; ++ni)
#pragma unroll
      for (int rg = 0; rg < 16; ++rg) acc[mi][ni][rg] = 0;

  int4v aA[4], aB[4], bA[2], bB[2];

  // ---- prologue: stage K-tiles 0..3; force {0,1}; preload k0(0) ----
#pragma unroll
  for (int p = 0; p < 4; ++p) {
    char* Wb = lds + p * 32768;
    GLOAD(gA0 + p * 64, Wb + ldst);
    GLOAD(gA1 + p * 64, Wb + 8192 + ldst);
    GLOAD(gB0 + p * 64, Wb + 16384 + ldst);
    GLOAD(gB1 + p * 64, Wb + 24576 + ldst);
  }
  asm volatile("s_waitcnt vmcnt(8)" ::: "memory");   // tiles 0,1 landed
  __builtin_amdgcn_s_barrier();
  __builtin_amdgcn_sched_barrier(0);
  RD(aA, bA, lds, aoff0, boff0)

  // ---- main loop: 32 super-steps of 2 K-tiles, each EXACTLY ONCE ----
  SUPER(0, 0, 1);                          // tiles 0,1 (bufs 2,3 from prologue)
  for (int S = 2; S <= 60; S += 2)         // SS 2..60; SS(60) stages 62,63
    SUPER(S, 1, 1);
  SUPER(62, 0, 0);                         // tiles 62,63; no stage/barrier

  // ---- epilogue: zp-correction + dequant + bias ----
  // C/D 32x32: col = lane&31, row = (rg&3) + 8*(rg>>2) + 4*(lane>>5)
  const int rb0 = tm * 256 + wmI * 128 + 4 * (lane >> 5);
  const int cb0 = tn * 256 + wnI * 64 + (lane & 31);
  const float ws0 = wscale[cb0],      ws1 = wscale[cb0 + 32];
  const float wo0 = woff[cb0],        wo1 = woff[cb0 + 32];
  const float bi0 = bias[cb0],        bi1 = bias[cb0 + 32];
#pragma unroll
  for (int mi = 0; mi < 4; ++mi) {
#pragma unroll
    for (int rg = 0; rg < 16; ++rg) {
      const int r = rb0 + mi * 32 + (rg & 3) + 8 * (rg >> 2);
      const float as_ = ascale[r];
      const float rs_ = (float)rsum[r];
      y[(size_t)r * DOUT + cb0]      = ((float)acc[mi][0][rg] + rs_ * wo0) * (as_ * ws0) + bi0;
      y[(size_t)r * DOUT + cb0 + 32] = ((float)acc[mi][1][rg] + rs_ * wo1) * (as_ * ws1) + bi1;
    }
  }
}

// ---------------------------------------------------------------------------
extern "C" void kernel_launch(void* const* d_in, const int* in_sizes, int n_in,
                              void* d_out, int out_size, void* d_ws, size_t ws_size,
                              hipStream_t stream) {
  const float* x      = (const float*)d_in[0];
  const int*   w      = (const int*)  d_in[1];
  const float* wscale = (const float*)d_in[2];
  const float* woff   = (const float*)d_in[3];
  const float* bias   = (const float*)d_in[4];
  float* y = (float*)d_out;

  char* ws = (char*)d_ws;
  char*  xq     = ws;                                 // 33,554,432 B
  char*  w8     = ws + (size_t)TOKENS * DIN;          // 16,777,216 B
  float* ascale = (float*)(w8 + (size_t)DOUT * DIN);  // 32,768 B
  int*   rsum   = (int*)(ascale + TOKENS);            // 32,768 B

  hipLaunchKernelGGL(quant_rows, dim3(TOKENS), dim3(256), 0, stream,
                     x, (int*)xq, ascale, rsum);
  hipLaunchKernelGGL(wconv, dim3((DOUT * DIN / 4) / 256), dim3(256), 0, stream,
                     w, (int*)w8);
  hipLaunchKernelGGL(gemm_i8, dim3((TOKENS / 256) * (DOUT / 256)), dim3(512), 0, stream,
                     xq, w8, ascale, rsum, wscale, woff, bias, y);
}